// Round 1
// baseline (483.764 us; speedup 1.0000x reference)
//
#include <hip/hip_runtime.h>
#include <stdint.h>

// E=8, T=4096, H=1024, I=512. fp32 I/O, bf16 MFMA compute internally.
// d_ws layout (192 MiB): xb | w1b | w2b | w3b | w4b | h1(=h3) | h2   (all bf16)

#define BM 128
#define BN 128
#define BK 64

typedef __attribute__((ext_vector_type(8))) short short8;
typedef __attribute__((ext_vector_type(4))) float float4v;

__device__ __forceinline__ uint16_t f32_to_bf16_rne(float f) {
    union { float f; uint32_t u; } v; v.f = f;
    uint32_t u = v.u;
    return (uint16_t)((u + 0x7FFFu + ((u >> 16) & 1u)) >> 16);
}

// fp32 -> bf16, no layout change. n must be divisible by 1024 (it is).
__global__ __launch_bounds__(256) void cvt_f32_bf16(const float* __restrict__ in,
                                                    uint16_t* __restrict__ out) {
    size_t i = ((size_t)blockIdx.x * 256 + threadIdx.x) * 4;
    float4 v = *(const float4*)(in + i);
    uint64_t pack = (uint64_t)f32_to_bf16_rne(v.x)
                  | ((uint64_t)f32_to_bf16_rne(v.y) << 16)
                  | ((uint64_t)f32_to_bf16_rne(v.z) << 32)
                  | ((uint64_t)f32_to_bf16_rne(v.w) << 48);
    *(uint64_t*)(out + i) = pack;
}

// transpose + convert: in [E][R][C] fp32 -> out [E][C][R] bf16 (weights -> [N][K])
__global__ __launch_bounds__(256) void tr_cvt(const float* __restrict__ in,
                                              uint16_t* __restrict__ out,
                                              int R, int C) {
    __shared__ float tile[32][33];
    int e = blockIdx.z;
    int r0 = blockIdx.y * 32, c0 = blockIdx.x * 32;
    const float* src = in + (size_t)e * R * C;
    uint16_t* dst = out + (size_t)e * R * C;
    int tx = threadIdx.x & 31;
    int ty = threadIdx.x >> 5;  // 0..7
#pragma unroll
    for (int j = 0; j < 32; j += 8)
        tile[ty + j][tx] = src[(size_t)(r0 + ty + j) * C + (c0 + tx)];
    __syncthreads();
#pragma unroll
    for (int j = 0; j < 32; j += 8)
        dst[(size_t)(c0 + ty + j) * R + (r0 + tx)] = f32_to_bf16_rne(tile[tx][ty + j]);
}

__device__ __forceinline__ void storeC(float* p, float v) { *p = v; }
__device__ __forceinline__ void storeC(uint16_t* p, float v) { *p = f32_to_bf16_rne(v); }

// C[e][M][N] = A[e][M][K] * B[e][N][K]^T   (both operands K-contiguous, bf16)
// 128x128 tile, BK=64, 4 waves (2x2), each wave 64x64 = 4x4 MFMA 16x16x32 tiles.
// LDS: linear [row][kb16B-slot] with kb' = kb ^ (row&7) swizzle (applied on the
// global-source side of global_load_lds; ds_read_b128 then lands at 2-way = free).
template <typename OutT>
__global__ __launch_bounds__(256, 2) void gemm_tn(
    const uint16_t* __restrict__ A,
    const uint16_t* __restrict__ B,
    OutT* __restrict__ C,
    int M, int N, int K)
{
    __shared__ __align__(16) uint16_t As[BM * BK];
    __shared__ __align__(16) uint16_t Bs[BN * BK];

    const int tid  = threadIdx.x;
    const int lane = tid & 63;
    const int wave = tid >> 6;          // 0..3
    const int wr = wave >> 1, wc = wave & 1;
    const int frow = lane & 15;         // MFMA within-tile row (A/B operand) / col (C)
    const int quad = lane >> 4;         // 0..3
    const int xm = frow & 7;            // swizzle xor mask for fragment reads

    const int e  = blockIdx.z;
    const int bm = blockIdx.y * BM;
    const int bn = blockIdx.x * BN;

    // staging: thread t covers LDS 16B slot (row = t>>3 + 32*i, slot = t&7);
    // global source block kb = (t&7) ^ (row&7)  (row&7 == (t>>3)&7 since 32*i ≡ 0 mod 8)
    const int srow = tid >> 3;                     // 0..31
    const int skb  = (tid & 7) ^ (srow & 7);
    const uint16_t* Ag = A + (size_t)e * M * K + (size_t)(bm + srow) * K + skb * 8;
    const uint16_t* Bg = B + (size_t)e * N * K + (size_t)(bn + srow) * K + skb * 8;

    float4v acc[4][4];
#pragma unroll
    for (int i = 0; i < 4; ++i)
#pragma unroll
        for (int j = 0; j < 4; ++j)
            acc[i][j] = (float4v){0.f, 0.f, 0.f, 0.f};

    char* AsB = (char*)As;
    char* BsB = (char*)Bs;

    for (int k0 = 0; k0 < K; k0 += BK) {
        __syncthreads();
#pragma unroll
        for (int i = 0; i < 4; ++i) {
            __builtin_amdgcn_global_load_lds(
                (const __attribute__((address_space(1))) void*)(Ag + k0 + (size_t)i * 32 * K),
                (__attribute__((address_space(3))) void*)(AsB + i * 4096 + wave * 1024),
                16, 0, 0);
        }
#pragma unroll
        for (int i = 0; i < 4; ++i) {
            __builtin_amdgcn_global_load_lds(
                (const __attribute__((address_space(1))) void*)(Bg + k0 + (size_t)i * 32 * K),
                (__attribute__((address_space(3))) void*)(BsB + i * 4096 + wave * 1024),
                16, 0, 0);
        }
        __syncthreads();
#pragma unroll
        for (int s = 0; s < 2; ++s) {
            short8 a[4], b[4];
            const int kb = ((s * 4 + quad) ^ xm) * 16;  // swizzled byte slot
#pragma unroll
            for (int t = 0; t < 4; ++t) {
                a[t] = *(const short8*)(AsB + (wr * 64 + t * 16 + frow) * 128 + kb);
                b[t] = *(const short8*)(BsB + (wc * 64 + t * 16 + frow) * 128 + kb);
            }
#pragma unroll
            for (int i = 0; i < 4; ++i)
#pragma unroll
                for (int j = 0; j < 4; ++j)
                    acc[i][j] = __builtin_amdgcn_mfma_f32_16x16x32_bf16(a[i], b[j], acc[i][j], 0, 0, 0);
        }
    }

    OutT* Ce = C + (size_t)e * M * N;
#pragma unroll
    for (int i = 0; i < 4; ++i) {
        int row0 = bm + wr * 64 + i * 16 + quad * 4;
#pragma unroll
        for (int j = 0; j < 4; ++j) {
            int col = bn + wc * 64 + j * 16 + frow;
#pragma unroll
            for (int r = 0; r < 4; ++r)
                storeC(&Ce[(size_t)(row0 + r) * N + col], acc[i][j][r]);
        }
    }
}

extern "C" void kernel_launch(void* const* d_in, const int* in_sizes, int n_in,
                              void* d_out, int out_size, void* d_ws, size_t ws_size,
                              hipStream_t stream) {
    const float* x  = (const float*)d_in[0];
    const float* w1 = (const float*)d_in[1];
    const float* w2 = (const float*)d_in[2];
    const float* w3 = (const float*)d_in[3];
    const float* w4 = (const float*)d_in[4];
    float* out = (float*)d_out;

    const int E = 8, T = 4096, H = 1024, I = 512;

    char* p = (char*)d_ws;
    uint16_t* xb  = (uint16_t*)p; p += (size_t)E * T * H * 2;   // 64 MiB
    uint16_t* w1b = (uint16_t*)p; p += (size_t)E * H * I * 2;   // 8 MiB, [E][I][H]
    uint16_t* w2b = (uint16_t*)p; p += (size_t)E * H * I * 2;   //        [E][H][I]
    uint16_t* w3b = (uint16_t*)p; p += (size_t)E * H * I * 2;
    uint16_t* w4b = (uint16_t*)p; p += (size_t)E * H * I * 2;
    uint16_t* h1  = (uint16_t*)p; p += (size_t)E * T * I * 2;   // 32 MiB
    uint16_t* h2  = (uint16_t*)p; p += (size_t)E * T * H * 2;   // 64 MiB
    uint16_t* h3  = h1;  // h1 dead once gemm3 runs

    // convert x (E*T*H = 33.5M elems, 4/thread)
    cvt_f32_bf16<<<dim3((unsigned)((size_t)E * T * H / 1024)), dim3(256), 0, stream>>>(x, xb);
    // weights: transpose to [N][K] bf16
    tr_cvt<<<dim3(I / 32, H / 32, E), dim3(256), 0, stream>>>(w1, w1b, H, I);
    tr_cvt<<<dim3(H / 32, I / 32, E), dim3(256), 0, stream>>>(w2, w2b, I, H);
    tr_cvt<<<dim3(I / 32, H / 32, E), dim3(256), 0, stream>>>(w3, w3b, H, I);
    tr_cvt<<<dim3(H / 32, I / 32, E), dim3(256), 0, stream>>>(w4, w4b, I, H);

    // h1 = x @ w1          [T,H]x[H,I] -> [T,I]
    gemm_tn<uint16_t><<<dim3(I / BN, T / BM, E), dim3(256), 0, stream>>>(xb, w1b, h1, T, I, H);
    // h2 = h1 @ w2         [T,I]x[I,H] -> [T,H]
    gemm_tn<uint16_t><<<dim3(H / BN, T / BM, E), dim3(256), 0, stream>>>(h1, w2b, h2, T, H, I);
    // h3 = h2 @ w3         [T,H]x[H,I] -> [T,I]
    gemm_tn<uint16_t><<<dim3(I / BN, T / BM, E), dim3(256), 0, stream>>>(h2, w3b, h3, T, I, H);
    // out = h3 @ w4        [T,I]x[I,H] -> [T,H], fp32 out
    gemm_tn<float><<<dim3(H / BN, T / BM, E), dim3(256), 0, stream>>>(h3, w4b, out, T, H, I);
}

// Round 2
// 479.162 us; speedup vs baseline: 1.0096x; 1.0096x over previous
//
#include <hip/hip_runtime.h>
#include <stdint.h>

// E=8, T=4096, H=1024, I=512. fp32 I/O, bf16 MFMA compute internally.
// d_ws layout (192 MiB): xb | w1b | w2b | w3b | w4b | h1(=h3) | h2   (all bf16)

#define BM 128
#define BN 128
#define BK 64

typedef __attribute__((ext_vector_type(8))) short short8;
typedef __attribute__((ext_vector_type(4))) float float4v;

__device__ __forceinline__ uint16_t f32_to_bf16_rne(float f) {
    union { float f; uint32_t u; } v; v.f = f;
    uint32_t u = v.u;
    return (uint16_t)((u + 0x7FFFu + ((u >> 16) & 1u)) >> 16);
}

// fp32 -> bf16, no layout change, 8 elems/thread (32B loads, 16B stores).
__global__ __launch_bounds__(256) void cvt_f32_bf16(const float* __restrict__ in,
                                                    uint16_t* __restrict__ out) {
    size_t i = ((size_t)blockIdx.x * 256 + threadIdx.x) * 8;
    float4 v0 = *(const float4*)(in + i);
    float4 v1 = *(const float4*)(in + i + 4);
    uint64_t p0 = (uint64_t)f32_to_bf16_rne(v0.x)
                | ((uint64_t)f32_to_bf16_rne(v0.y) << 16)
                | ((uint64_t)f32_to_bf16_rne(v0.z) << 32)
                | ((uint64_t)f32_to_bf16_rne(v0.w) << 48);
    uint64_t p1 = (uint64_t)f32_to_bf16_rne(v1.x)
                | ((uint64_t)f32_to_bf16_rne(v1.y) << 16)
                | ((uint64_t)f32_to_bf16_rne(v1.z) << 32)
                | ((uint64_t)f32_to_bf16_rne(v1.w) << 48);
    uint64_t* o = (uint64_t*)(out + i);
    o[0] = p0; o[1] = p1;
}

// Fused transpose+convert for all 4 weights: in [E][R][C] fp32 -> out [E][C][R] bf16.
// w1/w3: R=1024,C=512 (512 tiles/expert); w2/w4: R=512,C=1024 (512 tiles/expert).
// flat grid: bx = w*4096 + e*512 + tile.
__global__ __launch_bounds__(256) void tr_cvt_all(
    const float* __restrict__ i0, const float* __restrict__ i1,
    const float* __restrict__ i2, const float* __restrict__ i3,
    uint16_t* __restrict__ o0, uint16_t* __restrict__ o1,
    uint16_t* __restrict__ o2, uint16_t* __restrict__ o3) {
    __shared__ float tile[32][33];
    int bx = blockIdx.x;
    int w = bx >> 12;
    int t = bx & 4095;
    int e = t >> 9;
    int t2 = t & 511;
    const float* in = (w == 0) ? i0 : (w == 1) ? i1 : (w == 2) ? i2 : i3;
    uint16_t* out = (w == 0) ? o0 : (w == 1) ? o1 : (w == 2) ? o2 : o3;
    int R = (w & 1) ? 512 : 1024;      // w1,w3 are [H,I]; w2,w4 are [I,H]
    int C = (w & 1) ? 1024 : 512;
    int tilesX = C >> 5;               // 16 or 32
    int cx = t2 & (tilesX - 1);
    int ry = t2 / tilesX;
    int r0 = ry * 32, c0 = cx * 32;
    const float* src = in + (size_t)e * R * C;
    uint16_t* dst = out + (size_t)e * R * C;
    int tx = threadIdx.x & 31;
    int ty = threadIdx.x >> 5;  // 0..7
#pragma unroll
    for (int j = 0; j < 32; j += 8)
        tile[ty + j][tx] = src[(size_t)(r0 + ty + j) * C + (c0 + tx)];
    __syncthreads();
#pragma unroll
    for (int j = 0; j < 32; j += 8)
        dst[(size_t)(c0 + ty + j) * R + (r0 + tx)] = f32_to_bf16_rne(tile[tx][ty + j]);
}

__device__ __forceinline__ void storeC(float* p, float v) { *p = v; }
__device__ __forceinline__ void storeC(uint16_t* p, float v) { *p = f32_to_bf16_rne(v); }

// C[e][M][N] = A[e][M][K] * B[e][N][K]^T   (both operands K-contiguous, bf16)
// 128x128 tile, BK=64, 4 waves (2x2), each wave 64x64 = 4x4 MFMA 16x16x32 tiles.
// LDS slot swizzle kb' = kb ^ (row&7) (applied on the global-source side of
// global_load_lds): fragment ds_read_b128 spreads 64 lanes over all 8 slot
// groups (8 lanes/group = bank-balanced minimum), vs 16/group unswizzled.
// __launch_bounds__(256,3): cap VGPR ~170 -> 3 blocks/CU like m97 (164 VGPR);
// (256,2) left the compiler at 2 blocks/CU and cost latency hiding.
template <typename OutT>
__global__ __launch_bounds__(256, 3) void gemm_tn(
    const uint16_t* __restrict__ A,
    const uint16_t* __restrict__ B,
    OutT* __restrict__ C,
    int M, int N, int K)
{
    __shared__ __align__(16) uint16_t As[BM * BK];
    __shared__ __align__(16) uint16_t Bs[BN * BK];

    const int tid  = threadIdx.x;
    const int lane = tid & 63;
    const int wave = tid >> 6;          // 0..3
    const int wr = wave >> 1, wc = wave & 1;
    const int frow = lane & 15;         // MFMA within-tile row (A/B operand) / col (C)
    const int quad = lane >> 4;         // 0..3
    const int xm = frow & 7;            // swizzle xor mask for fragment reads

    const int e  = blockIdx.z;
    const int bm = blockIdx.y * BM;
    const int bn = blockIdx.x * BN;

    // staging: thread t covers LDS 16B slot (row = t>>3 + 32*i, slot = t&7);
    // global source block kb = (t&7) ^ (row&7)  (row&7 == (t>>3)&7 since 32*i ≡ 0 mod 8)
    const int srow = tid >> 3;                     // 0..31
    const int skb  = (tid & 7) ^ (srow & 7);
    const uint16_t* Ag = A + (size_t)e * M * K + (size_t)(bm + srow) * K + skb * 8;
    const uint16_t* Bg = B + (size_t)e * N * K + (size_t)(bn + srow) * K + skb * 8;

    float4v acc[4][4];
#pragma unroll
    for (int i = 0; i < 4; ++i)
#pragma unroll
        for (int j = 0; j < 4; ++j)
            acc[i][j] = (float4v){0.f, 0.f, 0.f, 0.f};

    char* AsB = (char*)As;
    char* BsB = (char*)Bs;

    for (int k0 = 0; k0 < K; k0 += BK) {
        __syncthreads();
#pragma unroll
        for (int i = 0; i < 4; ++i) {
            __builtin_amdgcn_global_load_lds(
                (const __attribute__((address_space(1))) void*)(Ag + k0 + (size_t)i * 32 * K),
                (__attribute__((address_space(3))) void*)(AsB + i * 4096 + wave * 1024),
                16, 0, 0);
        }
#pragma unroll
        for (int i = 0; i < 4; ++i) {
            __builtin_amdgcn_global_load_lds(
                (const __attribute__((address_space(1))) void*)(Bg + k0 + (size_t)i * 32 * K),
                (__attribute__((address_space(3))) void*)(BsB + i * 4096 + wave * 1024),
                16, 0, 0);
        }
        __syncthreads();
#pragma unroll
        for (int s = 0; s < 2; ++s) {
            short8 a[4], b[4];
            const int kb = ((s * 4 + quad) ^ xm) * 16;  // swizzled byte slot
#pragma unroll
            for (int t = 0; t < 4; ++t) {
                a[t] = *(const short8*)(AsB + (wr * 64 + t * 16 + frow) * 128 + kb);
                b[t] = *(const short8*)(BsB + (wc * 64 + t * 16 + frow) * 128 + kb);
            }
#pragma unroll
            for (int i = 0; i < 4; ++i)
#pragma unroll
                for (int j = 0; j < 4; ++j)
                    acc[i][j] = __builtin_amdgcn_mfma_f32_16x16x32_bf16(a[i], b[j], acc[i][j], 0, 0, 0);
        }
    }

    OutT* Ce = C + (size_t)e * M * N;
#pragma unroll
    for (int i = 0; i < 4; ++i) {
        int row0 = bm + wr * 64 + i * 16 + quad * 4;
#pragma unroll
        for (int j = 0; j < 4; ++j) {
            int col = bn + wc * 64 + j * 16 + frow;
#pragma unroll
            for (int r = 0; r < 4; ++r)
                storeC(&Ce[(size_t)(row0 + r) * N + col], acc[i][j][r]);
        }
    }
}

extern "C" void kernel_launch(void* const* d_in, const int* in_sizes, int n_in,
                              void* d_out, int out_size, void* d_ws, size_t ws_size,
                              hipStream_t stream) {
    const float* x  = (const float*)d_in[0];
    const float* w1 = (const float*)d_in[1];
    const float* w2 = (const float*)d_in[2];
    const float* w3 = (const float*)d_in[3];
    const float* w4 = (const float*)d_in[4];
    float* out = (float*)d_out;

    const int E = 8, T = 4096, H = 1024, I = 512;

    char* p = (char*)d_ws;
    uint16_t* xb  = (uint16_t*)p; p += (size_t)E * T * H * 2;   // 64 MiB
    uint16_t* w1b = (uint16_t*)p; p += (size_t)E * H * I * 2;   // 8 MiB, [E][I][H]
    uint16_t* w2b = (uint16_t*)p; p += (size_t)E * H * I * 2;   //        [E][H][I]
    uint16_t* w3b = (uint16_t*)p; p += (size_t)E * H * I * 2;
    uint16_t* w4b = (uint16_t*)p; p += (size_t)E * H * I * 2;
    uint16_t* h1  = (uint16_t*)p; p += (size_t)E * T * I * 2;   // 32 MiB
    uint16_t* h2  = (uint16_t*)p; p += (size_t)E * T * H * 2;   // 64 MiB
    uint16_t* h3  = h1;  // h1 dead once gemm3 runs

    // convert x (E*T*H = 33.5M elems, 8/thread)
    cvt_f32_bf16<<<dim3((unsigned)((size_t)E * T * H / 2048)), dim3(256), 0, stream>>>(x, xb);
    // all 4 weight transposes in one launch: 4 * 8 * 512 tiles
    tr_cvt_all<<<dim3(4 * 8 * 512), dim3(256), 0, stream>>>(w1, w2, w3, w4, w1b, w2b, w3b, w4b);

    // h1 = x @ w1          [T,H]x[H,I] -> [T,I]
    gemm_tn<uint16_t><<<dim3(I / BN, T / BM, E), dim3(256), 0, stream>>>(xb, w1b, h1, T, I, H);
    // h2 = h1 @ w2         [T,I]x[I,H] -> [T,H]
    gemm_tn<uint16_t><<<dim3(H / BN, T / BM, E), dim3(256), 0, stream>>>(h1, w2b, h2, T, H, I);
    // h3 = h2 @ w3         [T,H]x[H,I] -> [T,I]
    gemm_tn<uint16_t><<<dim3(I / BN, T / BM, E), dim3(256), 0, stream>>>(h2, w3b, h3, T, I, H);
    // out = h3 @ w4        [T,I]x[I,H] -> [T,H], fp32 out
    gemm_tn<float><<<dim3(H / BN, T / BM, E), dim3(256), 0, stream>>>(h3, w4b, out, T, H, I);
}

// Round 3
// 472.222 us; speedup vs baseline: 1.0244x; 1.0147x over previous
//
#include <hip/hip_runtime.h>
#include <stdint.h>

// E=8, T=4096, H=1024, I=512. fp32 I/O, bf16 MFMA compute internally.
// d_ws layout (128 MiB): w1b | w2b | w3b | w4b | h1(=h3) | h2   (all bf16)
// x conversion is fused into GEMM1's A-staging (fp32 buffer_load -> cvt -> ds_write).

#define BM 128
#define BN 128
#define BK 64

typedef __attribute__((ext_vector_type(8))) short short8;
typedef __attribute__((ext_vector_type(4))) float float4v;

__device__ __forceinline__ uint16_t f32_to_bf16_rne(float f) {
    union { float f; uint32_t u; } v; v.f = f;
    uint32_t u = v.u;
    return (uint16_t)((u + 0x7FFFu + ((u >> 16) & 1u)) >> 16);
}

// Fused transpose+convert for all 4 weights: in [E][R][C] fp32 -> out [E][C][R] bf16.
// w1/w3: R=1024,C=512; w2/w4: R=512,C=1024. 512 tiles/expert each.
__global__ __launch_bounds__(256) void tr_cvt_all(
    const float* __restrict__ i0, const float* __restrict__ i1,
    const float* __restrict__ i2, const float* __restrict__ i3,
    uint16_t* __restrict__ o0, uint16_t* __restrict__ o1,
    uint16_t* __restrict__ o2, uint16_t* __restrict__ o3) {
    __shared__ float tile[32][33];
    int bx = blockIdx.x;
    int w = bx >> 12;
    int t = bx & 4095;
    int e = t >> 9;
    int t2 = t & 511;
    const float* in = (w == 0) ? i0 : (w == 1) ? i1 : (w == 2) ? i2 : i3;
    uint16_t* out = (w == 0) ? o0 : (w == 1) ? o1 : (w == 2) ? o2 : o3;
    int R = (w & 1) ? 512 : 1024;      // w1,w3 are [H,I]; w2,w4 are [I,H]
    int C = (w & 1) ? 1024 : 512;
    int tilesX = C >> 5;               // 16 or 32
    int cx = t2 & (tilesX - 1);
    int ry = t2 / tilesX;
    int r0 = ry * 32, c0 = cx * 32;
    const float* src = in + (size_t)e * R * C;
    uint16_t* dst = out + (size_t)e * R * C;
    int tx = threadIdx.x & 31;
    int ty = threadIdx.x >> 5;  // 0..7
#pragma unroll
    for (int j = 0; j < 32; j += 8)
        tile[ty + j][tx] = src[(size_t)(r0 + ty + j) * C + (c0 + tx)];
    __syncthreads();
#pragma unroll
    for (int j = 0; j < 32; j += 8)
        dst[(size_t)(c0 + ty + j) * R + (r0 + tx)] = f32_to_bf16_rne(tile[tx][ty + j]);
}

__device__ __forceinline__ void storeC(float* p, float v) { *p = v; }
__device__ __forceinline__ void storeC(uint16_t* p, float v) { *p = f32_to_bf16_rne(v); }

// C[e][M][N] = A[e][M][K] * B[e][N][K]^T.  B is bf16 K-contiguous; A is bf16
// (A_FP32=false, staged via global_load_lds) or fp32 (A_FP32=true, staged via
// buffer_load float4 x2 -> cvt -> ds_write_b128 with the same swizzled slot map).
// 128x128 tile, BK=64, 4 waves (2x2), each wave 64x64 = 4x4 MFMA 16x16x32 tiles.
// LDS slot swizzle kb' = kb ^ (row&7): fragment ds_read_b128 lands 2 lanes per
// 4-bank group per quarter-wave (free) instead of 16-way conflicts unswizzled.
template <typename OutT, typename AT>
__global__ __launch_bounds__(256, 3) void gemm_tn(
    const AT* __restrict__ A,
    const uint16_t* __restrict__ B,
    OutT* __restrict__ C,
    int M, int N, int K)
{
    constexpr bool A_FP32 = sizeof(AT) == 4;
    __shared__ __align__(16) uint16_t As[BM * BK];
    __shared__ __align__(16) uint16_t Bs[BN * BK];

    const int tid  = threadIdx.x;
    const int lane = tid & 63;
    const int wave = tid >> 6;          // 0..3
    const int wr = wave >> 1, wc = wave & 1;
    const int frow = lane & 15;
    const int quad = lane >> 4;
    const int xm = frow & 7;            // fragment-read xor mask

    const int e  = blockIdx.z;
    const int bm = blockIdx.y * BM;
    const int bn = blockIdx.x * BN;

    // staging map: thread t covers LDS 16B slot (row = t>>3 + 32*i, slot = t&7);
    // global source block kb = (t&7) ^ (row&7)   (row&7 == (t>>3)&7 since 32*i ≡ 0 mod 8)
    const int srow = tid >> 3;                     // 0..31
    const int skb  = (tid & 7) ^ (srow & 7);
    const AT* Ag = A + (size_t)e * M * K + (size_t)(bm + srow) * K + skb * 8;
    const uint16_t* Bg = B + (size_t)e * N * K + (size_t)(bn + srow) * K + skb * 8;

    float4v acc[4][4];
#pragma unroll
    for (int i = 0; i < 4; ++i)
#pragma unroll
        for (int j = 0; j < 4; ++j)
            acc[i][j] = (float4v){0.f, 0.f, 0.f, 0.f};

    char* AsB = (char*)As;
    char* BsB = (char*)Bs;
    const int lds_slot_off = (tid & 7) * 16;       // LDS byte slot this thread fills

    for (int k0 = 0; k0 < K; k0 += BK) {
        __syncthreads();
        if constexpr (A_FP32) {
#pragma unroll
            for (int i = 0; i < 4; ++i) {
                const float* src = (const float*)Ag + k0 + (size_t)i * 32 * K;
                float4 v0 = *(const float4*)(src);
                float4 v1 = *(const float4*)(src + 4);
                short8 s;
                s[0] = (short)f32_to_bf16_rne(v0.x);
                s[1] = (short)f32_to_bf16_rne(v0.y);
                s[2] = (short)f32_to_bf16_rne(v0.z);
                s[3] = (short)f32_to_bf16_rne(v0.w);
                s[4] = (short)f32_to_bf16_rne(v1.x);
                s[5] = (short)f32_to_bf16_rne(v1.y);
                s[6] = (short)f32_to_bf16_rne(v1.z);
                s[7] = (short)f32_to_bf16_rne(v1.w);
                *(short8*)(AsB + (srow + 32 * i) * 128 + lds_slot_off) = s;
            }
        } else {
#pragma unroll
            for (int i = 0; i < 4; ++i) {
                __builtin_amdgcn_global_load_lds(
                    (const __attribute__((address_space(1))) void*)((const uint16_t*)Ag + k0 + (size_t)i * 32 * K),
                    (__attribute__((address_space(3))) void*)(AsB + i * 4096 + wave * 1024),
                    16, 0, 0);
            }
        }
#pragma unroll
        for (int i = 0; i < 4; ++i) {
            __builtin_amdgcn_global_load_lds(
                (const __attribute__((address_space(1))) void*)(Bg + k0 + (size_t)i * 32 * K),
                (__attribute__((address_space(3))) void*)(BsB + i * 4096 + wave * 1024),
                16, 0, 0);
        }
        __syncthreads();
#pragma unroll
        for (int s = 0; s < 2; ++s) {
            short8 a[4], b[4];
            const int kb = ((s * 4 + quad) ^ xm) * 16;  // swizzled byte slot
#pragma unroll
            for (int t = 0; t < 4; ++t) {
                a[t] = *(const short8*)(AsB + (wr * 64 + t * 16 + frow) * 128 + kb);
                b[t] = *(const short8*)(BsB + (wc * 64 + t * 16 + frow) * 128 + kb);
            }
#pragma unroll
            for (int i = 0; i < 4; ++i)
#pragma unroll
                for (int j = 0; j < 4; ++j)
                    acc[i][j] = __builtin_amdgcn_mfma_f32_16x16x32_bf16(a[i], b[j], acc[i][j], 0, 0, 0);
        }
    }

    OutT* Ce = C + (size_t)e * M * N;
#pragma unroll
    for (int i = 0; i < 4; ++i) {
        int row0 = bm + wr * 64 + i * 16 + quad * 4;
#pragma unroll
        for (int j = 0; j < 4; ++j) {
            int col = bn + wc * 64 + j * 16 + frow;
#pragma unroll
            for (int r = 0; r < 4; ++r)
                storeC(&Ce[(size_t)(row0 + r) * N + col], acc[i][j][r]);
        }
    }
}

extern "C" void kernel_launch(void* const* d_in, const int* in_sizes, int n_in,
                              void* d_out, int out_size, void* d_ws, size_t ws_size,
                              hipStream_t stream) {
    const float* x  = (const float*)d_in[0];
    const float* w1 = (const float*)d_in[1];
    const float* w2 = (const float*)d_in[2];
    const float* w3 = (const float*)d_in[3];
    const float* w4 = (const float*)d_in[4];
    float* out = (float*)d_out;

    const int E = 8, T = 4096, H = 1024, I = 512;

    char* p = (char*)d_ws;
    uint16_t* w1b = (uint16_t*)p; p += (size_t)E * H * I * 2;   // 8 MiB, [E][I][H]
    uint16_t* w2b = (uint16_t*)p; p += (size_t)E * H * I * 2;   //        [E][H][I]
    uint16_t* w3b = (uint16_t*)p; p += (size_t)E * H * I * 2;
    uint16_t* w4b = (uint16_t*)p; p += (size_t)E * H * I * 2;
    uint16_t* h1  = (uint16_t*)p; p += (size_t)E * T * I * 2;   // 32 MiB
    uint16_t* h2  = (uint16_t*)p; p += (size_t)E * T * H * 2;   // 64 MiB
    uint16_t* h3  = h1;  // h1 dead once gemm3 runs

    // all 4 weight transposes in one launch: 4 * 8 * 512 tiles
    tr_cvt_all<<<dim3(4 * 8 * 512), dim3(256), 0, stream>>>(w1, w2, w3, w4, w1b, w2b, w3b, w4b);

    // h1 = x @ w1          [T,H]x[H,I] -> [T,I]   (A read directly as fp32)
    gemm_tn<uint16_t, float><<<dim3(I / BN, T / BM, E), dim3(256), 0, stream>>>(x, w1b, h1, T, I, H);
    // h2 = h1 @ w2         [T,I]x[I,H] -> [T,H]
    gemm_tn<uint16_t, uint16_t><<<dim3(H / BN, T / BM, E), dim3(256), 0, stream>>>(h1, w2b, h2, T, H, I);
    // h3 = h2 @ w3         [T,H]x[H,I] -> [T,I]
    gemm_tn<uint16_t, uint16_t><<<dim3(I / BN, T / BM, E), dim3(256), 0, stream>>>(h2, w3b, h3, T, I, H);
    // out = h3 @ w4        [T,I]x[I,H] -> [T,H], fp32 out
    gemm_tn<float, uint16_t><<<dim3(H / BN, T / BM, E), dim3(256), 0, stream>>>(h3, w4b, out, T, H, I);
}